// Round 3
// 746.840 us; speedup vs baseline: 1.2712x; 1.2712x over previous
//
#include <hip/hip_runtime.h>

#define B_ 32
#define C_ 256
#define CI_ 128
#define N_ 4096

typedef unsigned int u32;
typedef unsigned short u16;
typedef __attribute__((ext_vector_type(8))) short s8v;   // 8 bf16 (4 VGPR)
typedef __attribute__((ext_vector_type(4))) float f4v;   // 4 fp32 acc

__device__ __forceinline__ u16 f2bs(float f) {   // fp32 -> bf16 bits (RNE)
    union { float f; u32 u; } c; c.f = f;
    u32 u = c.u + 0x7FFFu + ((c.u >> 16) & 1u);
    return (u16)(u >> 16);
}
__device__ __forceinline__ float bs2f(u16 s) {   // bf16 bits -> fp32
    union { u32 u; float f; } c; c.u = ((u32)s) << 16; return c.f;
}
// split float -> (hi bf16, lo bf16) with x ~= hi + lo  (RNE both — proven numerics)
__device__ __forceinline__ void split2(float x, u16& h, u16& l) {
    h = f2bs(x);
    l = f2bs(x - bs2f(h));
}

#define MFMA16(a, b, c) __builtin_amdgcn_mfma_f32_16x16x32_bf16((a), (b), (c), 0, 0, 0)

// ---------------------------------------------------------------------------
// K1: row sums sx[b,t] = sum_n X[b,t,n]. grid (C,B), block 64 (one wave).
// ---------------------------------------------------------------------------
__global__ __launch_bounds__(64) void sx_kernel(
    const float* __restrict__ x, float* __restrict__ sx)
{
    const int t = blockIdx.x, b = blockIdx.y, lane = threadIdx.x;
    const float4* row = (const float4*)(x + ((size_t)(b * C_ + t)) * N_);
    float s = 0.f;
    for (int k = lane; k < N_ / 4; k += 64) {
        float4 v = row[k];
        s += v.x + v.y + v.z + v.w;
    }
    #pragma unroll
    for (int off = 32; off > 0; off >>= 1) s += __shfl_down(s, off);
    if (lane == 0) sx[b * C_ + t] = s;
}

// ---------------------------------------------------------------------------
// K2: Gram partials Gp[ks][b] = X_b[:, ks*512:(ks+1)*512] · (same)^T via MFMA,
// hi/lo 3-pass. grid (2 j, 2 i, B*8): blockIdx.z = b*8 + ks, K-chunk = 512.
// 1024 blocks = 4 blocks/CU (was 128 blocks = 0.5/CU -> 5.7% occupancy).
// Partials land in d_out scratch: out[b, 128..255, :] (2MB/batch = 8 x 256KB),
// reduced by g_reduce into ws G before anything reads G.
// ---------------------------------------------------------------------------
__global__ __launch_bounds__(256) void gram_mfma(
    const float* __restrict__ x, float* __restrict__ outp)
{
    const int zb = blockIdx.z;
    const int b = zb >> 3, ks = zb & 7;
    const int i0 = blockIdx.y * 128, j0 = blockIdx.x * 128;
    const int tid = threadIdx.x;
    const int w = tid >> 6, l = tid & 63, lm = l & 15, lq = l >> 4;

    __shared__ u16 Ah[128 * 40], Al[128 * 40], Bh[128 * 40], Bl[128 * 40];

    f4v acc[2][8];
    #pragma unroll
    for (int mi = 0; mi < 2; ++mi)
        #pragma unroll
        for (int ni = 0; ni < 8; ++ni) acc[mi][ni] = (f4v){0.f, 0.f, 0.f, 0.f};

    const int srow = tid >> 3;          // 0..31
    const int sc4  = (tid & 7) * 4;     // 0,4,...,28

    const int kbeg = ks * 512, kend = kbeg + 512;
    for (int k0 = kbeg; k0 < kend; k0 += 32) {
        #pragma unroll
        for (int rr = 0; rr < 4; ++rr) {
            int row = rr * 32 + srow;
            float4 va = *(const float4*)(x + (((size_t)(b * C_ + i0 + row)) << 12) + k0 + sc4);
            float4 vb = *(const float4*)(x + (((size_t)(b * C_ + j0 + row)) << 12) + k0 + sc4);
            u16 h0, h1, h2, h3, l0, l1, l2, l3;
            split2(va.x, h0, l0); split2(va.y, h1, l1);
            split2(va.z, h2, l2); split2(va.w, h3, l3);
            *(uint2*)&Ah[row * 40 + sc4] = make_uint2((u32)h0 | ((u32)h1 << 16),
                                                      (u32)h2 | ((u32)h3 << 16));
            *(uint2*)&Al[row * 40 + sc4] = make_uint2((u32)l0 | ((u32)l1 << 16),
                                                      (u32)l2 | ((u32)l3 << 16));
            split2(vb.x, h0, l0); split2(vb.y, h1, l1);
            split2(vb.z, h2, l2); split2(vb.w, h3, l3);
            *(uint2*)&Bh[row * 40 + sc4] = make_uint2((u32)h0 | ((u32)h1 << 16),
                                                      (u32)h2 | ((u32)h3 << 16));
            *(uint2*)&Bl[row * 40 + sc4] = make_uint2((u32)l0 | ((u32)l1 << 16),
                                                      (u32)l2 | ((u32)l3 << 16));
        }
        __syncthreads();

        const int kofs = lq * 8;
        s8v ah[2], al2[2];
        #pragma unroll
        for (int mi = 0; mi < 2; ++mi) {
            int arow = w * 32 + mi * 16 + lm;
            ah[mi]  = *(const s8v*)&Ah[arow * 40 + kofs];
            al2[mi] = *(const s8v*)&Al[arow * 40 + kofs];
        }
        #pragma unroll
        for (int ni = 0; ni < 8; ++ni) {
            int brow = ni * 16 + lm;
            s8v bh = *(const s8v*)&Bh[brow * 40 + kofs];
            s8v bl = *(const s8v*)&Bl[brow * 40 + kofs];
            #pragma unroll
            for (int mi = 0; mi < 2; ++mi) {
                acc[mi][ni] = MFMA16(ah[mi],  bh, acc[mi][ni]);
                acc[mi][ni] = MFMA16(ah[mi],  bl, acc[mi][ni]);
                acc[mi][ni] = MFMA16(al2[mi], bh, acc[mi][ni]);
            }
        }
        __syncthreads();
    }
    // epilogue: partial into out-scratch. D[row=(lq*4+r)][col=lm] per tile.
    float* Gp = outp + (((size_t)(b * 256 + 128)) << 12) + (size_t)ks * 65536;
    #pragma unroll
    for (int mi = 0; mi < 2; ++mi)
        #pragma unroll
        for (int ni = 0; ni < 8; ++ni)
            #pragma unroll
            for (int r = 0; r < 4; ++r) {
                int gi = i0 + w * 32 + mi * 16 + lq * 4 + r;
                int gj = j0 + ni * 16 + lm;
                Gp[(size_t)gi * 256 + gj] = acc[mi][ni][r];
            }
}

// ---------------------------------------------------------------------------
// K2b: G[b] = sum_ks Gp[ks][b]. grid 2048, block 256, float4 per thread.
// ---------------------------------------------------------------------------
__global__ __launch_bounds__(256) void g_reduce(
    const float* __restrict__ outp, float* __restrict__ G)
{
    int f = blockIdx.x * 256 + threadIdx.x;      // float4 index, 0..524287
    int b = f >> 14;                              // 16384 float4 per batch
    int r4 = (f & 16383) << 2;
    const float* src = outp + (((size_t)(b * 256 + 128)) << 12) + r4;
    float4 s = *(const float4*)(src);
    #pragma unroll
    for (int k = 1; k < 8; ++k) {
        float4 v = *(const float4*)(src + (size_t)k * 65536);
        s.x += v.x; s.y += v.y; s.z += v.z; s.w += v.w;
    }
    *(float4*)(G + ((size_t)b << 16) + r4) = s;
}

// ---------------------------------------------------------------------------
// K3: A1[b] = Tw · G[b]  ([128,256] fp32). grid (2,B), block (16,16). VALU.
// ---------------------------------------------------------------------------
__global__ __launch_bounds__(256) void a1_kernel(
    const float* __restrict__ tw, const float* __restrict__ G,
    float* __restrict__ A1)
{
    const int b = blockIdx.y, u0 = blockIdx.x * 128;
    const int tx = threadIdx.x, ty = threadIdx.y, tid = ty * 16 + tx;
    __shared__ float Tws[32][129], Gs[32][129];
    float acc[8][8] = {};
    for (int t0 = 0; t0 < C_; t0 += 32) {
        for (int r = 0; r < 16; ++r) {
            int e = tid + 256 * r;
            int ii = e >> 5, tk = e & 31;
            Tws[tk][ii] = tw[ii * C_ + t0 + tk];
        }
        for (int r = 0; r < 16; ++r) {
            int e = tid + 256 * r;
            int tk = e >> 7, uu = e & 127;
            Gs[tk][uu] = G[(size_t)b * 65536 + (size_t)(t0 + tk) * 256 + u0 + uu];
        }
        __syncthreads();
        for (int k = 0; k < 32; ++k) {
            float a[8], c[8];
            #pragma unroll
            for (int u = 0; u < 8; ++u) a[u] = Tws[k][ty * 8 + u];
            #pragma unroll
            for (int v = 0; v < 8; ++v) c[v] = Gs[k][tx * 8 + v];
            #pragma unroll
            for (int u = 0; u < 8; ++u)
                #pragma unroll
                for (int v = 0; v < 8; ++v) acc[u][v] += a[u] * c[v];
        }
        __syncthreads();
    }
    #pragma unroll
    for (int u = 0; u < 8; ++u)
        #pragma unroll
        for (int v = 0; v < 8; ++v)
            A1[(size_t)b * 32768 + (size_t)(ty * 8 + u) * 256 + u0 + tx * 8 + v] = acc[u][v];
}

// ---------------------------------------------------------------------------
// K4: F = A1·Pwᵀ + t1·pbᵀ + tb·t2ᵀ + N·tb·pbᵀ, row-softmax -> fsm fp32.
// grid (B), block (16,16). VALU.
// ---------------------------------------------------------------------------
__global__ __launch_bounds__(256) void f_kernel(
    const float* __restrict__ A1,
    const float* __restrict__ tw, const float* __restrict__ tb,
    const float* __restrict__ pw, const float* __restrict__ pb,
    const float* __restrict__ sx, float* __restrict__ fsm)
{
    const int b = blockIdx.x;
    const int tx = threadIdx.x, ty = threadIdx.y, tid = ty * 16 + tx;
    __shared__ float sxs[256], t12[256];
    __shared__ float As[32][129], Ps[32][129];
    sxs[tid] = sx[b * 256 + tid];
    __syncthreads();
    {
        float s = 0.f;
        if (tid < 128) {
            for (int t = 0; t < 256; ++t) s += tw[tid * 256 + t] * sxs[t];
        } else {
            int j = tid - 128;
            for (int t = 0; t < 256; ++t) s += pw[j * 256 + t] * sxs[t];
        }
        t12[tid] = s;
    }
    float acc[8][8] = {};
    for (int u0 = 0; u0 < C_; u0 += 32) {
        for (int r = 0; r < 16; ++r) {
            int e = tid + 256 * r;
            int ii = e >> 5, uk = e & 31;
            As[uk][ii] = A1[(size_t)b * 32768 + (size_t)ii * 256 + u0 + uk];
            Ps[uk][ii] = pw[ii * 256 + u0 + uk];
        }
        __syncthreads();
        for (int k = 0; k < 32; ++k) {
            float a[8], c[8];
            #pragma unroll
            for (int u = 0; u < 8; ++u) a[u] = As[k][ty * 8 + u];
            #pragma unroll
            for (int v = 0; v < 8; ++v) c[v] = Ps[k][tx * 8 + v];
            #pragma unroll
            for (int u = 0; u < 8; ++u)
                #pragma unroll
                for (int v = 0; v < 8; ++v) acc[u][v] += a[u] * c[v];
        }
        __syncthreads();
    }
    float tbv[8], pbv[8], t2v[8];
    #pragma unroll
    for (int u = 0; u < 8; ++u) tbv[u] = tb[ty * 8 + u];
    #pragma unroll
    for (int v = 0; v < 8; ++v) {
        int j = tx * 8 + v;
        pbv[v] = pb[j];
        t2v[v] = t12[128 + j];
    }
    #pragma unroll
    for (int u = 0; u < 8; ++u) {
        const int i = ty * 8 + u;
        float t1i = t12[i];
        float row[8];
        #pragma unroll
        for (int v = 0; v < 8; ++v)
            row[v] = acc[u][v] + t1i * pbv[v] + tbv[u] * (t2v[v] + 4096.0f * pbv[v]);
        float m = row[0];
        #pragma unroll
        for (int v = 1; v < 8; ++v) m = fmaxf(m, row[v]);
        m = fmaxf(m, __shfl_xor(m, 1));
        m = fmaxf(m, __shfl_xor(m, 2));
        m = fmaxf(m, __shfl_xor(m, 4));
        m = fmaxf(m, __shfl_xor(m, 8));
        float s = 0.f;
        #pragma unroll
        for (int v = 0; v < 8; ++v) s += __expf(row[v] - m);
        s += __shfl_xor(s, 1);
        s += __shfl_xor(s, 2);
        s += __shfl_xor(s, 4);
        s += __shfl_xor(s, 8);
        float inv = 1.0f / s;
        #pragma unroll
        for (int v = 0; v < 8; ++v)
            fsm[(size_t)b * 16384 + (size_t)i * 128 + tx * 8 + v] = __expf(row[v] - m) * inv;
    }
}

// ---------------------------------------------------------------------------
// K5: Mh[b] = bf16(f_smᵀ · Gw) ([128 j,256 t]); rj[b,j] = f_smᵀ·gb.
// grid (2,B), block (16,16). VALU (small).
// ---------------------------------------------------------------------------
__global__ __launch_bounds__(256) void m_kernel(
    const float* __restrict__ fsm, const float* __restrict__ gw,
    const float* __restrict__ gb,
    u16* __restrict__ Mh, float* __restrict__ rj)
{
    const int b = blockIdx.y, t0 = blockIdx.x * 128;
    const int tx = threadIdx.x, ty = threadIdx.y, tid = ty * 16 + tx;
    __shared__ float Fs[32][129], Gs[32][129];
    float acc[8][8] = {};
    for (int i0 = 0; i0 < CI_; i0 += 32) {
        for (int r = 0; r < 16; ++r) {
            int e = tid + 256 * r;
            int ik = e >> 7, jj = e & 127;
            Fs[ik][jj] = fsm[(size_t)b * 16384 + (size_t)(i0 + ik) * 128 + jj];
            Gs[ik][jj] = gw[(i0 + ik) * 256 + t0 + jj];
        }
        __syncthreads();
        for (int k = 0; k < 32; ++k) {
            float a[8], c[8];
            #pragma unroll
            for (int u = 0; u < 8; ++u) a[u] = Fs[k][ty * 8 + u];
            #pragma unroll
            for (int v = 0; v < 8; ++v) c[v] = Gs[k][tx * 8 + v];
            #pragma unroll
            for (int u = 0; u < 8; ++u)
                #pragma unroll
                for (int v = 0; v < 8; ++v) acc[u][v] += a[u] * c[v];
        }
        __syncthreads();
    }
    #pragma unroll
    for (int u = 0; u < 8; ++u)
        #pragma unroll
        for (int v = 0; v < 8; ++v)
            Mh[(size_t)b * 32768 + (size_t)(ty * 8 + u) * 256 + t0 + tx * 8 + v] = f2bs(acc[u][v]);
    if (blockIdx.x == 0 && tid < 128) {
        float s = 0.f;
        for (int i = 0; i < 128; ++i)
            s += fsm[(size_t)b * 16384 + (size_t)i * 128 + tid] * gb[i];
        rj[b * 128 + tid] = s;
    }
}

// ---------------------------------------------------------------------------
// K5b: Owh = bf16(ow), [256,128]. grid (32), block 256, 4 elems/thread.
// ---------------------------------------------------------------------------
__global__ __launch_bounds__(256) void owh_kernel(
    const float* __restrict__ ow, u16* __restrict__ Owh)
{
    int i = (blockIdx.x * 256 + threadIdx.x) * 4;
    float4 v = *(const float4*)(ow + i);
    u16 a = f2bs(v.x), b = f2bs(v.y), c = f2bs(v.z), d = f2bs(v.w);
    *(uint2*)&Owh[i] = make_uint2((u32)a | ((u32)b << 16), (u32)c | ((u32)d << 16));
}

// ---------------------------------------------------------------------------
// K6a: W[s,n] = sum_t Mh[s,t]·X[t,n] + rj[s] stored scrambled as
// Y[z, 128q+s] (z=n>>5, q=n&31) fp32 into out[b, 0:128, :] (scratch).
// grid (32 n-chunks of 128, B). Coalesced x loads; LDS-transposed B tile
// with XOR chunk swizzle; fragment stores are full 64B lines.
// ---------------------------------------------------------------------------
__global__ __launch_bounds__(256) void y_kernel(
    const u16* __restrict__ Mh, const float* __restrict__ rj,
    const float* __restrict__ x, float* __restrict__ outp)
{
    const int nb = blockIdx.x, b = blockIdx.y;
    const int n0 = nb * 128;
    const int tid = threadIdx.x;
    const int w = tid >> 6, l = tid & 63, lm = l & 15, lq = l >> 4;

    __shared__ u16 Bs[128 * 40];   // [n-local][t-chunk swizzled], bf16

    f4v acc[2][8];
    #pragma unroll
    for (int mi = 0; mi < 2; ++mi)
        #pragma unroll
        for (int ni = 0; ni < 8; ++ni) acc[mi][ni] = (f4v){0.f, 0.f, 0.f, 0.f};

    const int tt = tid >> 3;            // 0..31 (t within k-step)
    const int nn0 = (tid & 7) * 16;     // n-local base, step 16

    for (int t0 = 0; t0 < C_; t0 += 32) {
        // stage X^T: load 16 floats along n (coalesced), transpose into Bs
        const float* xr = x + (((size_t)(b * C_ + t0 + tt)) << 12) + n0 + nn0;
        float vv[16];
        *(float4*)&vv[0]  = *(const float4*)(xr + 0);
        *(float4*)&vv[4]  = *(const float4*)(xr + 4);
        *(float4*)&vv[8]  = *(const float4*)(xr + 8);
        *(float4*)&vv[12] = *(const float4*)(xr + 12);
        const int chb = tt >> 3, tl = tt & 7;
        #pragma unroll
        for (int j = 0; j < 16; ++j) {
            int row = nn0 + j;
            int ch = chb ^ ((row >> 4) & 3);   // XOR swizzle vs bank degeneracy
            Bs[row * 40 + ch * 8 + tl] = f2bs(vv[j]);
        }
        __syncthreads();

        s8v af[2];
        #pragma unroll
        for (int mi = 0; mi < 2; ++mi)
            af[mi] = *(const s8v*)(Mh + (size_t)b * 32768
                     + (size_t)(w * 32 + mi * 16 + lm) * 256 + t0 + lq * 8);
        #pragma unroll
        for (int ni = 0; ni < 8; ++ni) {
            int row = ni * 16 + lm;
            s8v bf = *(const s8v*)&Bs[row * 40 + ((lq ^ ((row >> 4) & 3)) << 3)];
            acc[0][ni] = MFMA16(af[0], bf, acc[0][ni]);
            acc[1][ni] = MFMA16(af[1], bf, acc[1][ni]);
        }
        __syncthreads();
    }
    // epilogue: Y[z][128q + s] = acc + rj[s]; 4 consecutive s -> float4
    #pragma unroll
    for (int mi = 0; mi < 2; ++mi) {
        const int s0 = w * 32 + mi * 16 + lq * 4;
        float rjv[4];
        #pragma unroll
        for (int r = 0; r < 4; ++r) rjv[r] = rj[b * 128 + s0 + r];
        #pragma unroll
        for (int ni = 0; ni < 8; ++ni) {
            int nn = ni * 16 + lm;
            int z = (n0 + nn) >> 5;
            int q = nn & 31;
            float4 st;
            st.x = acc[mi][ni][0] + rjv[0];
            st.y = acc[mi][ni][1] + rjv[1];
            st.z = acc[mi][ni][2] + rjv[2];
            st.w = acc[mi][ni][3] + rjv[3];
            *(float4*)(outp + (((size_t)(b * C_ + z)) << 12) + 128 * q + s0) = st;
        }
    }
}

// ---------------------------------------------------------------------------
// K6b: out[b,o,p] = sum_z Owh[o,z]·Y[z,p] + ob[o] + x[b,o,p].
// grid (32 p-chunks of 128, B). Y read from out[b,0:128,:]; each block
// stages its full Y column-tile into LDS (barrier) BEFORE writing its own
// p-columns, so the in-place overwrite is race-free (col ranges disjoint
// across blocks). Phase-2 MFMA structure identical to the proven kernel.
// ---------------------------------------------------------------------------
__global__ __launch_bounds__(256) void out_kernel(
    float* outp, const u16* __restrict__ Owh, const float* __restrict__ ob,
    const float* __restrict__ x)
{
    const int pt = blockIdx.x, b = blockIdx.y;
    const int p0 = pt * 128;
    const int tid = threadIdx.x;
    const int w = tid >> 6, l = tid & 63, lm = l & 15, lq = l >> 4;

    __shared__ u16 Zs[128 * 136];   // [p-local][z-chunk swizzled], bf16

    const int zz = tid >> 3;            // 0..31
    const int pp0 = (tid & 7) * 16;
    #pragma unroll
    for (int zb = 0; zb < 128; zb += 32) {
        const int zc = zb + zz;
        const float* yr = outp + (((size_t)(b * C_ + zc)) << 12) + p0 + pp0;
        float vv[16];
        *(float4*)&vv[0]  = *(const float4*)(yr + 0);
        *(float4*)&vv[4]  = *(const float4*)(yr + 4);
        *(float4*)&vv[8]  = *(const float4*)(yr + 8);
        *(float4*)&vv[12] = *(const float4*)(yr + 12);
        const int chb = zc >> 3, zl = zc & 7;
        #pragma unroll
        for (int j = 0; j < 16; ++j) {
            int row = pp0 + j;
            int ch = chb ^ ((row >> 4) & 3);
            Zs[row * 136 + ch * 8 + zl] = f2bs(vv[j]);
        }
    }
    __syncthreads();

    f4v acc[4][8];
    #pragma unroll
    for (int mi = 0; mi < 4; ++mi)
        #pragma unroll
        for (int ni = 0; ni < 8; ++ni) acc[mi][ni] = (f4v){0.f, 0.f, 0.f, 0.f};

    #pragma unroll
    for (int kc = 0; kc < 4; ++kc) {
        s8v af[4];
        #pragma unroll
        for (int mi = 0; mi < 4; ++mi)
            af[mi] = *(const s8v*)(Owh + (size_t)(w * 64 + mi * 16 + lm) * 128
                                   + kc * 32 + lq * 8);
        #pragma unroll
        for (int ni = 0; ni < 8; ++ni) {
            int row = ni * 16 + lm;
            s8v bf = *(const s8v*)&Zs[row * 136 + kc * 32
                                      + ((lq ^ ((row >> 4) & 3)) << 3)];
            #pragma unroll
            for (int mi = 0; mi < 4; ++mi)
                acc[mi][ni] = MFMA16(af[mi], bf, acc[mi][ni]);
        }
    }
    // epilogue: out = acc + ob + x
    #pragma unroll
    for (int mi = 0; mi < 4; ++mi) {
        #pragma unroll
        for (int r = 0; r < 4; ++r) {
            int o = w * 64 + mi * 16 + lq * 4 + r;
            float bo = ob[o];
            #pragma unroll
            for (int ni = 0; ni < 8; ++ni) {
                int p = p0 + ni * 16 + lm;
                size_t idx = (((size_t)(b * C_ + o)) << 12) + p;
                outp[idx] = acc[mi][ni][r] + bo + x[idx];
            }
        }
    }
}

extern "C" void kernel_launch(void* const* d_in, const int* in_sizes, int n_in,
                              void* d_out, int out_size, void* d_ws, size_t ws_size,
                              hipStream_t stream) {
    const float* x  = (const float*)d_in[0];
    const float* tw = (const float*)d_in[1];
    const float* tb = (const float*)d_in[2];
    const float* pw = (const float*)d_in[3];
    const float* pb = (const float*)d_in[4];
    const float* gw = (const float*)d_in[5];
    const float* gb = (const float*)d_in[6];
    const float* ow = (const float*)d_in[7];
    const float* ob = (const float*)d_in[8];
    float* out = (float*)d_out;

    // workspace (unchanged layout, 16.1 MB):
    //   G   fp32 [B,256,256] @ 0
    //   sx  fp32 [B,256]     @  8,388,608
    //   A1  fp32 [B,128,256] @  8,421,376
    //   fsm fp32 [B,128,128] @ 12,615,680
    //   rj  fp32 [B,128]     @ 14,712,832
    //   Mh  bf16 [B,128,256] @ 14,729,216
    //   Owh bf16 [256,128]   @ 16,826,368
    // d_out scratch usage (all dead before final out_kernel writes):
    //   rows 128..255 of each batch: 8 Gram split-K partials (8 x 256KB)
    //   rows   0..127 of each batch: Y[z,p] fp32 intermediate
    char* ws = (char*)d_ws;
    float* G   = (float*)(ws);
    float* sx  = (float*)(ws + 8388608ull);
    float* A1  = (float*)(ws + 8421376ull);
    float* fsm = (float*)(ws + 12615680ull);
    float* rj  = (float*)(ws + 14712832ull);
    u16*   Mh  = (u16*)(ws + 14729216ull);
    u16*   Owh = (u16*)(ws + 16826368ull);

    dim3 blk2(16, 16);
    hipLaunchKernelGGL(sx_kernel, dim3(C_, B_), dim3(64), 0, stream, x, sx);
    hipLaunchKernelGGL(gram_mfma, dim3(2, 2, B_ * 8), dim3(256), 0, stream, x, out);
    hipLaunchKernelGGL(g_reduce, dim3(2048), dim3(256), 0, stream, out, G);
    hipLaunchKernelGGL(a1_kernel, dim3(2, B_), blk2, 0, stream, tw, G, A1);
    hipLaunchKernelGGL(f_kernel, dim3(B_), blk2, 0, stream, A1, tw, tb, pw, pb, sx, fsm);
    hipLaunchKernelGGL(m_kernel, dim3(2, B_), blk2, 0, stream, fsm, gw, gb, Mh, rj);
    hipLaunchKernelGGL(owh_kernel, dim3(32), dim3(256), 0, stream, ow, Owh);
    hipLaunchKernelGGL(y_kernel, dim3(32, B_), dim3(256), 0, stream, Mh, rj, x, out);
    hipLaunchKernelGGL(out_kernel, dim3(32, B_), dim3(256), 0, stream, out, Owh, ob, x);
}

// Round 4
// 516.389 us; speedup vs baseline: 1.8386x; 1.4463x over previous
//
#include <hip/hip_runtime.h>

#define B_ 32
#define C_ 256
#define CI_ 128
#define N_ 4096

typedef unsigned int u32;
typedef unsigned short u16;
typedef __attribute__((ext_vector_type(8))) short s8v;   // 8 bf16 (4 VGPR)
typedef __attribute__((ext_vector_type(4))) float f4v;   // 4 fp32 acc

__device__ __forceinline__ u16 f2bs(float f) {   // fp32 -> bf16 bits (RNE)
    union { float f; u32 u; } c; c.f = f;
    u32 u = c.u + 0x7FFFu + ((c.u >> 16) & 1u);
    return (u16)(u >> 16);
}
__device__ __forceinline__ float bs2f(u16 s) {   // bf16 bits -> fp32
    union { u32 u; float f; } c; c.u = ((u32)s) << 16; return c.f;
}
// split float -> (hi bf16, lo bf16) with x ~= hi + lo  (RNE both — proven numerics)
__device__ __forceinline__ void split2(float x, u16& h, u16& l) {
    h = f2bs(x);
    l = f2bs(x - bs2f(h));
}

#define MFMA16(a, b, c) __builtin_amdgcn_mfma_f32_16x16x32_bf16((a), (b), (c), 0, 0, 0)

// ---------------------------------------------------------------------------
// K1: row sums sx[b,t] = sum_n X[b,t,n]. grid (C,B), block 64 (one wave).
// ---------------------------------------------------------------------------
__global__ __launch_bounds__(64) void sx_kernel(
    const float* __restrict__ x, float* __restrict__ sx)
{
    const int t = blockIdx.x, b = blockIdx.y, lane = threadIdx.x;
    const float4* row = (const float4*)(x + ((size_t)(b * C_ + t)) * N_);
    float s = 0.f;
    for (int k = lane; k < N_ / 4; k += 64) {
        float4 v = row[k];
        s += v.x + v.y + v.z + v.w;
    }
    #pragma unroll
    for (int off = 32; off > 0; off >>= 1) s += __shfl_down(s, off);
    if (lane == 0) sx[b * C_ + t] = s;
}

// ---------------------------------------------------------------------------
// K2: Gram partials (split-K=8) via MFMA hi/lo 3-pass. grid (2,2,B*8).
// Partials -> d_out scratch rows 128..255 per batch; g_reduce sums into G.
// ---------------------------------------------------------------------------
__global__ __launch_bounds__(256) void gram_mfma(
    const float* __restrict__ x, float* __restrict__ outp)
{
    const int zb = blockIdx.z;
    const int b = zb >> 3, ks = zb & 7;
    const int i0 = blockIdx.y * 128, j0 = blockIdx.x * 128;
    const int tid = threadIdx.x;
    const int w = tid >> 6, l = tid & 63, lm = l & 15, lq = l >> 4;

    __shared__ u16 Ah[128 * 40], Al[128 * 40], Bh[128 * 40], Bl[128 * 40];

    f4v acc[2][8];
    #pragma unroll
    for (int mi = 0; mi < 2; ++mi)
        #pragma unroll
        for (int ni = 0; ni < 8; ++ni) acc[mi][ni] = (f4v){0.f, 0.f, 0.f, 0.f};

    const int srow = tid >> 3;          // 0..31
    const int sc4  = (tid & 7) * 4;     // 0,4,...,28

    const int kbeg = ks * 512, kend = kbeg + 512;
    for (int k0 = kbeg; k0 < kend; k0 += 32) {
        #pragma unroll
        for (int rr = 0; rr < 4; ++rr) {
            int row = rr * 32 + srow;
            float4 va = *(const float4*)(x + (((size_t)(b * C_ + i0 + row)) << 12) + k0 + sc4);
            float4 vb = *(const float4*)(x + (((size_t)(b * C_ + j0 + row)) << 12) + k0 + sc4);
            u16 h0, h1, h2, h3, l0, l1, l2, l3;
            split2(va.x, h0, l0); split2(va.y, h1, l1);
            split2(va.z, h2, l2); split2(va.w, h3, l3);
            *(uint2*)&Ah[row * 40 + sc4] = make_uint2((u32)h0 | ((u32)h1 << 16),
                                                      (u32)h2 | ((u32)h3 << 16));
            *(uint2*)&Al[row * 40 + sc4] = make_uint2((u32)l0 | ((u32)l1 << 16),
                                                      (u32)l2 | ((u32)l3 << 16));
            split2(vb.x, h0, l0); split2(vb.y, h1, l1);
            split2(vb.z, h2, l2); split2(vb.w, h3, l3);
            *(uint2*)&Bh[row * 40 + sc4] = make_uint2((u32)h0 | ((u32)h1 << 16),
                                                      (u32)h2 | ((u32)h3 << 16));
            *(uint2*)&Bl[row * 40 + sc4] = make_uint2((u32)l0 | ((u32)l1 << 16),
                                                      (u32)l2 | ((u32)l3 << 16));
        }
        __syncthreads();

        const int kofs = lq * 8;
        s8v ah[2], al2[2];
        #pragma unroll
        for (int mi = 0; mi < 2; ++mi) {
            int arow = w * 32 + mi * 16 + lm;
            ah[mi]  = *(const s8v*)&Ah[arow * 40 + kofs];
            al2[mi] = *(const s8v*)&Al[arow * 40 + kofs];
        }
        #pragma unroll
        for (int ni = 0; ni < 8; ++ni) {
            int brow = ni * 16 + lm;
            s8v bh = *(const s8v*)&Bh[brow * 40 + kofs];
            s8v bl = *(const s8v*)&Bl[brow * 40 + kofs];
            #pragma unroll
            for (int mi = 0; mi < 2; ++mi) {
                acc[mi][ni] = MFMA16(ah[mi],  bh, acc[mi][ni]);
                acc[mi][ni] = MFMA16(ah[mi],  bl, acc[mi][ni]);
                acc[mi][ni] = MFMA16(al2[mi], bh, acc[mi][ni]);
            }
        }
        __syncthreads();
    }
    float* Gp = outp + (((size_t)(b * 256 + 128)) << 12) + (size_t)ks * 65536;
    #pragma unroll
    for (int mi = 0; mi < 2; ++mi)
        #pragma unroll
        for (int ni = 0; ni < 8; ++ni)
            #pragma unroll
            for (int r = 0; r < 4; ++r) {
                int gi = i0 + w * 32 + mi * 16 + lq * 4 + r;
                int gj = j0 + ni * 16 + lm;
                Gp[(size_t)gi * 256 + gj] = acc[mi][ni][r];
            }
}

// ---------------------------------------------------------------------------
// K2b: G[b] = sum_ks Gp[ks][b]. grid 2048, block 256, float4 per thread.
// ---------------------------------------------------------------------------
__global__ __launch_bounds__(256) void g_reduce(
    const float* __restrict__ outp, float* __restrict__ G)
{
    int f = blockIdx.x * 256 + threadIdx.x;
    int b = f >> 14;
    int r4 = (f & 16383) << 2;
    const float* src = outp + (((size_t)(b * 256 + 128)) << 12) + r4;
    float4 s = *(const float4*)(src);
    #pragma unroll
    for (int k = 1; k < 8; ++k) {
        float4 v = *(const float4*)(src + (size_t)k * 65536);
        s.x += v.x; s.y += v.y; s.z += v.z; s.w += v.w;
    }
    *(float4*)(G + ((size_t)b << 16) + r4) = s;
}

// ---------------------------------------------------------------------------
// K3 (fused mid-chain): per batch b, one block of 512 threads (8 waves, 2x4):
//   phase 0: t1/t2 = Tw·sx, Pw·sx                      (VALU, LDS t12)
//   phase A: A1 = Tw·G        [128,256] -> LDS hi/lo   (MFMA 3-pass)
//   phase B: F = A1·Pwᵀ + rank-1 terms -> LDS fp32     (MFMA 3-pass)
//   softmax rows of F -> fsmᵀ hi/lo in LDS (transposed at write)
//   rj[j] = Σ_i fsm[i,j]·gb[i]
//   phase C: Mh[j,t] = Σ_i fsmᵀ[j,i]·Gw[i,t] -> global bf16 (MFMA 3-pass,
//            Gw transposed through XOR-swizzled LDS tiles, y_kernel pattern)
// LDS regions time-multiplexed (max concurrent 154 KB).
// Replaces a1_kernel + f_kernel + m_kernel (were ~250 µs at 3% occupancy).
// ---------------------------------------------------------------------------
__global__ __launch_bounds__(512, 2) void mid_kernel(
    const float* __restrict__ G,
    const float* __restrict__ tw, const float* __restrict__ tb,
    const float* __restrict__ pw, const float* __restrict__ pb,
    const float* __restrict__ sx,
    const float* __restrict__ gw, const float* __restrict__ gb,
    u16* __restrict__ Mh, float* __restrict__ rj)
{
    const int b = blockIdx.x;
    const int tid = threadIdx.x;
    const int w = tid >> 6, l = tid & 63, lm = l & 15, lq = l >> 4;
    const int wr = w >> 2, wc = w & 3;          // wave grid 2 x 4

    __shared__ __attribute__((aligned(16))) char smem[157696];
    // persistent:
    float* t12s = (float*)(smem + 155648);       // [256]
    float* sxs  = (float*)(smem + 156672);       // [256]
    // phase A staging (dead before A1 written):
    u16* TwTh = (u16*)(smem);                    // [128][40]
    u16* TwTl = (u16*)(smem + 10240);
    u16* GTh  = (u16*)(smem + 20480);            // [256][40]
    u16* GTl  = (u16*)(smem + 40960);            // ..61440
    // A1 (phases A->B):
    u16* A1h = (u16*)(smem);                     // [128][264] ..67584
    u16* A1l = (u16*)(smem + 67584);             // ..135168
    // phase B staging:
    u16* PwTh = (u16*)(smem + 135168);           // [128][40]
    u16* PwTl = (u16*)(smem + 145408);           // ..155648
    // F (after phase B; A1 dead):
    float* Ff = (float*)(smem);                  // [128][136] ..69632
    // fsm^T hi/lo (softmax -> phase C):
    u16* fsmTh = (u16*)(smem + 69632);           // [128][136] ..104448
    u16* fsmTl = (u16*)(smem + 104448);          // ..139264
    // phase C staging (F dead):
    u16* GwTh = (u16*)(smem);                    // [256][40]
    u16* GwTl = (u16*)(smem + 20480);            // ..40960

    // ---------------- phase 0: sx stage + t12 ----------------
    if (tid < 256) sxs[tid] = sx[b * 256 + tid];
    __syncthreads();
    {
        const int oid = tid >> 1, half = tid & 1;
        const float* wrow = (oid < 128) ? (tw + oid * 256) : (pw + (oid - 128) * 256);
        float s = 0.f;
        for (int t = half * 128; t < half * 128 + 128; ++t) s += wrow[t] * sxs[t];
        s += __shfl_xor(s, 1);
        if (half == 0) t12s[oid] = s;
    }
    __syncthreads();

    // ---------------- phase A: A1 = Tw · G ----------------
    f4v acc[4][4];
    #pragma unroll
    for (int mi = 0; mi < 4; ++mi)
        #pragma unroll
        for (int ni = 0; ni < 4; ++ni) acc[mi][ni] = (f4v){0.f, 0.f, 0.f, 0.f};

    for (int t0 = 0; t0 < C_; t0 += 32) {
        { // stage Tw tile [128 i][32 t]
            int i = tid >> 2, tg = (tid & 3) * 8;
            float4 v0 = *(const float4*)(tw + i * 256 + t0 + tg);
            float4 v1 = *(const float4*)(tw + i * 256 + t0 + tg + 4);
            u16 h0,h1,h2,h3,l0,l1,l2,l3;
            split2(v0.x,h0,l0); split2(v0.y,h1,l1); split2(v0.z,h2,l2); split2(v0.w,h3,l3);
            *(uint2*)&TwTh[i*40+tg]   = make_uint2((u32)h0|((u32)h1<<16),(u32)h2|((u32)h3<<16));
            *(uint2*)&TwTl[i*40+tg]   = make_uint2((u32)l0|((u32)l1<<16),(u32)l2|((u32)l3<<16));
            split2(v1.x,h0,l0); split2(v1.y,h1,l1); split2(v1.z,h2,l2); split2(v1.w,h3,l3);
            *(uint2*)&TwTh[i*40+tg+4] = make_uint2((u32)h0|((u32)h1<<16),(u32)h2|((u32)h3<<16));
            *(uint2*)&TwTl[i*40+tg+4] = make_uint2((u32)l0|((u32)l1<<16),(u32)l2|((u32)l3<<16));
        }
        { // stage G tile [256 u][32 t] (G symmetric: rows = cols)
            int u = tid >> 1, tg = (tid & 1) * 16;
            const float* gp = G + ((size_t)b << 16) + (size_t)u * 256 + t0 + tg;
            #pragma unroll
            for (int q = 0; q < 4; ++q) {
                float4 v = *(const float4*)(gp + q * 4);
                u16 h0,h1,h2,h3,l0,l1,l2,l3;
                split2(v.x,h0,l0); split2(v.y,h1,l1); split2(v.z,h2,l2); split2(v.w,h3,l3);
                *(uint2*)&GTh[u*40+tg+q*4] = make_uint2((u32)h0|((u32)h1<<16),(u32)h2|((u32)h3<<16));
                *(uint2*)&GTl[u*40+tg+q*4] = make_uint2((u32)l0|((u32)l1<<16),(u32)l2|((u32)l3<<16));
            }
        }
        __syncthreads();
        const int kofs = lq * 8;
        s8v ah[4], al[4];
        #pragma unroll
        for (int mi = 0; mi < 4; ++mi) {
            int ai = wr * 64 + mi * 16 + lm;
            ah[mi] = *(const s8v*)&TwTh[ai * 40 + kofs];
            al[mi] = *(const s8v*)&TwTl[ai * 40 + kofs];
        }
        #pragma unroll
        for (int ni = 0; ni < 4; ++ni) {
            int bu = wc * 64 + ni * 16 + lm;
            s8v bh = *(const s8v*)&GTh[bu * 40 + kofs];
            s8v bl = *(const s8v*)&GTl[bu * 40 + kofs];
            #pragma unroll
            for (int mi = 0; mi < 4; ++mi) {
                acc[mi][ni] = MFMA16(ah[mi], bh, acc[mi][ni]);
                acc[mi][ni] = MFMA16(ah[mi], bl, acc[mi][ni]);
                acc[mi][ni] = MFMA16(al[mi], bh, acc[mi][ni]);
            }
        }
        __syncthreads();
    }
    // write A1 hi/lo into LDS
    #pragma unroll
    for (int mi = 0; mi < 4; ++mi)
        #pragma unroll
        for (int ni = 0; ni < 4; ++ni)
            #pragma unroll
            for (int r = 0; r < 4; ++r) {
                int i = wr * 64 + mi * 16 + lq * 4 + r;
                int u = wc * 64 + ni * 16 + lm;
                u16 h, lo; split2(acc[mi][ni][r], h, lo);
                A1h[i * 264 + u] = h; A1l[i * 264 + u] = lo;
            }
    __syncthreads();

    // ---------------- phase B: F = A1 · Pwᵀ ----------------
    f4v acc2[4][2];
    #pragma unroll
    for (int mi = 0; mi < 4; ++mi)
        #pragma unroll
        for (int ni = 0; ni < 2; ++ni) acc2[mi][ni] = (f4v){0.f, 0.f, 0.f, 0.f};

    for (int u0 = 0; u0 < C_; u0 += 32) {
        { // stage Pw tile [128 j][32 u]
            int j = tid >> 2, ug = (tid & 3) * 8;
            float4 v0 = *(const float4*)(pw + j * 256 + u0 + ug);
            float4 v1 = *(const float4*)(pw + j * 256 + u0 + ug + 4);
            u16 h0,h1,h2,h3,l0,l1,l2,l3;
            split2(v0.x,h0,l0); split2(v0.y,h1,l1); split2(v0.z,h2,l2); split2(v0.w,h3,l3);
            *(uint2*)&PwTh[j*40+ug]   = make_uint2((u32)h0|((u32)h1<<16),(u32)h2|((u32)h3<<16));
            *(uint2*)&PwTl[j*40+ug]   = make_uint2((u32)l0|((u32)l1<<16),(u32)l2|((u32)l3<<16));
            split2(v1.x,h0,l0); split2(v1.y,h1,l1); split2(v1.z,h2,l2); split2(v1.w,h3,l3);
            *(uint2*)&PwTh[j*40+ug+4] = make_uint2((u32)h0|((u32)h1<<16),(u32)h2|((u32)h3<<16));
            *(uint2*)&PwTl[j*40+ug+4] = make_uint2((u32)l0|((u32)l1<<16),(u32)l2|((u32)l3<<16));
        }
        __syncthreads();
        const int kofs = lq * 8;
        s8v ah[4], al[4];
        #pragma unroll
        for (int mi = 0; mi < 4; ++mi) {
            int ai = wr * 64 + mi * 16 + lm;
            ah[mi] = *(const s8v*)&A1h[ai * 264 + u0 + kofs];
            al[mi] = *(const s8v*)&A1l[ai * 264 + u0 + kofs];
        }
        #pragma unroll
        for (int ni = 0; ni < 2; ++ni) {
            int bj = wc * 32 + ni * 16 + lm;
            s8v bh = *(const s8v*)&PwTh[bj * 40 + kofs];
            s8v bl = *(const s8v*)&PwTl[bj * 40 + kofs];
            #pragma unroll
            for (int mi = 0; mi < 4; ++mi) {
                acc2[mi][ni] = MFMA16(ah[mi], bh, acc2[mi][ni]);
                acc2[mi][ni] = MFMA16(ah[mi], bl, acc2[mi][ni]);
                acc2[mi][ni] = MFMA16(al[mi], bh, acc2[mi][ni]);
            }
        }
        __syncthreads();
    }
    // epilogue: rank-1 terms, write F fp32 to LDS (A1 dead)
    #pragma unroll
    for (int ni = 0; ni < 2; ++ni) {
        int j = wc * 32 + ni * 16 + lm;
        float pbv = pb[j], t2v = t12s[128 + j];
        #pragma unroll
        for (int mi = 0; mi < 4; ++mi)
            #pragma unroll
            for (int r = 0; r < 4; ++r) {
                int i = wr * 64 + mi * 16 + lq * 4 + r;
                float val = acc2[mi][ni][r] + t12s[i] * pbv
                          + tb[i] * (t2v + 4096.0f * pbv);
                Ff[i * 136 + j] = val;
            }
    }
    __syncthreads();

    // ---------------- softmax rows of F -> fsmT hi/lo ----------------
    {
        const int i = tid >> 2, sub = tid & 3;   // 4 lanes per row
        float vv[32];
        #pragma unroll
        for (int c = 0; c < 32; ++c) vv[c] = Ff[i * 136 + sub * 32 + c];
        float m = vv[0];
        #pragma unroll
        for (int c = 1; c < 32; ++c) m = fmaxf(m, vv[c]);
        m = fmaxf(m, __shfl_xor(m, 1));
        m = fmaxf(m, __shfl_xor(m, 2));
        float s = 0.f;
        #pragma unroll
        for (int c = 0; c < 32; ++c) { vv[c] = __expf(vv[c] - m); s += vv[c]; }
        s += __shfl_xor(s, 1);
        s += __shfl_xor(s, 2);
        float inv = 1.0f / s;
        #pragma unroll
        for (int c = 0; c < 32; ++c) {
            int j = sub * 32 + c;
            u16 h, lo; split2(vv[c] * inv, h, lo);
            fsmTh[j * 136 + i] = h; fsmTl[j * 136 + i] = lo;   // transposed
        }
    }
    __syncthreads();

    // rj[j] = sum_i fsm[i,j] * gb[i]
    if (tid < 128) {
        float s = 0.f;
        for (int i = 0; i < 128; ++i)
            s += (bs2f(fsmTh[tid * 136 + i]) + bs2f(fsmTl[tid * 136 + i])) * gb[i];
        rj[b * 128 + tid] = s;
    }

    // ---------------- phase C: Mh[j,t] = fsmT · GwT ----------------
    f4v acc3[4][4];
    #pragma unroll
    for (int mi = 0; mi < 4; ++mi)
        #pragma unroll
        for (int ni = 0; ni < 4; ++ni) acc3[mi][ni] = (f4v){0.f, 0.f, 0.f, 0.f};

    for (int i0 = 0; i0 < CI_; i0 += 32) {
        { // stage GwT tile [256 t][32 i] with XOR swizzle (y_kernel pattern)
            int ir = tid >> 4, tg = (tid & 15) * 16;
            const float* gp = gw + (size_t)(i0 + ir) * 256 + tg;
            float vv[16];
            *(float4*)&vv[0]  = *(const float4*)(gp + 0);
            *(float4*)&vv[4]  = *(const float4*)(gp + 4);
            *(float4*)&vv[8]  = *(const float4*)(gp + 8);
            *(float4*)&vv[12] = *(const float4*)(gp + 12);
            const int chb = ir >> 3, il = ir & 7;
            #pragma unroll
            for (int jj = 0; jj < 16; ++jj) {
                int t = tg + jj;
                int ch = chb ^ ((t >> 4) & 3);
                u16 h, lo; split2(vv[jj], h, lo);
                GwTh[t * 40 + ch * 8 + il] = h;
                GwTl[t * 40 + ch * 8 + il] = lo;
            }
        }
        __syncthreads();
        s8v ah[4], al[4];
        #pragma unroll
        for (int mi = 0; mi < 4; ++mi) {
            int aj = wr * 64 + mi * 16 + lm;
            ah[mi] = *(const s8v*)&fsmTh[aj * 136 + i0 + lq * 8];
            al[mi] = *(const s8v*)&fsmTl[aj * 136 + i0 + lq * 8];
        }
        #pragma unroll
        for (int ni = 0; ni < 4; ++ni) {
            int bt = wc * 64 + ni * 16 + lm;
            int co = (lq ^ ((bt >> 4) & 3)) << 3;
            s8v bh = *(const s8v*)&GwTh[bt * 40 + co];
            s8v bl = *(const s8v*)&GwTl[bt * 40 + co];
            #pragma unroll
            for (int mi = 0; mi < 4; ++mi) {
                acc3[mi][ni] = MFMA16(ah[mi], bh, acc3[mi][ni]);
                acc3[mi][ni] = MFMA16(ah[mi], bl, acc3[mi][ni]);
                acc3[mi][ni] = MFMA16(al[mi], bh, acc3[mi][ni]);
            }
        }
        __syncthreads();
    }
    // epilogue: Mh[b, j, t] bf16
    #pragma unroll
    for (int mi = 0; mi < 4; ++mi)
        #pragma unroll
        for (int ni = 0; ni < 4; ++ni)
            #pragma unroll
            for (int r = 0; r < 4; ++r) {
                int j = wr * 64 + mi * 16 + lq * 4 + r;
                int t = wc * 64 + ni * 16 + lm;
                Mh[(size_t)b * 32768 + (size_t)j * 256 + t] = f2bs(acc3[mi][ni][r]);
            }
}

// ---------------------------------------------------------------------------
// K5b: Owh = bf16(ow), [256,128]. grid (32), block 256, 4 elems/thread.
// ---------------------------------------------------------------------------
__global__ __launch_bounds__(256) void owh_kernel(
    const float* __restrict__ ow, u16* __restrict__ Owh)
{
    int i = (blockIdx.x * 256 + threadIdx.x) * 4;
    float4 v = *(const float4*)(ow + i);
    u16 a = f2bs(v.x), b = f2bs(v.y), c = f2bs(v.z), d = f2bs(v.w);
    *(uint2*)&Owh[i] = make_uint2((u32)a | ((u32)b << 16), (u32)c | ((u32)d << 16));
}

// ---------------------------------------------------------------------------
// K6a: W[s,n] = sum_t Mh[s,t]·X[t,n] + rj[s] stored scrambled as
// Y[z, 128q+s] fp32 into out[b, 0:128, :] (scratch). grid (32, B).
// ---------------------------------------------------------------------------
__global__ __launch_bounds__(256) void y_kernel(
    const u16* __restrict__ Mh, const float* __restrict__ rj,
    const float* __restrict__ x, float* __restrict__ outp)
{
    const int nb = blockIdx.x, b = blockIdx.y;
    const int n0 = nb * 128;
    const int tid = threadIdx.x;
    const int w = tid >> 6, l = tid & 63, lm = l & 15, lq = l >> 4;

    __shared__ u16 Bs[128 * 40];

    f4v acc[2][8];
    #pragma unroll
    for (int mi = 0; mi < 2; ++mi)
        #pragma unroll
        for (int ni = 0; ni < 8; ++ni) acc[mi][ni] = (f4v){0.f, 0.f, 0.f, 0.f};

    const int tt = tid >> 3;
    const int nn0 = (tid & 7) * 16;

    for (int t0 = 0; t0 < C_; t0 += 32) {
        const float* xr = x + (((size_t)(b * C_ + t0 + tt)) << 12) + n0 + nn0;
        float vv[16];
        *(float4*)&vv[0]  = *(const float4*)(xr + 0);
        *(float4*)&vv[4]  = *(const float4*)(xr + 4);
        *(float4*)&vv[8]  = *(const float4*)(xr + 8);
        *(float4*)&vv[12] = *(const float4*)(xr + 12);
        const int chb = tt >> 3, tl = tt & 7;
        #pragma unroll
        for (int j = 0; j < 16; ++j) {
            int row = nn0 + j;
            int ch = chb ^ ((row >> 4) & 3);
            Bs[row * 40 + ch * 8 + tl] = f2bs(vv[j]);
        }
        __syncthreads();

        s8v af[2];
        #pragma unroll
        for (int mi = 0; mi < 2; ++mi)
            af[mi] = *(const s8v*)(Mh + (size_t)b * 32768
                     + (size_t)(w * 32 + mi * 16 + lm) * 256 + t0 + lq * 8);
        #pragma unroll
        for (int ni = 0; ni < 8; ++ni) {
            int row = ni * 16 + lm;
            s8v bf = *(const s8v*)&Bs[row * 40 + ((lq ^ ((row >> 4) & 3)) << 3)];
            acc[0][ni] = MFMA16(af[0], bf, acc[0][ni]);
            acc[1][ni] = MFMA16(af[1], bf, acc[1][ni]);
        }
        __syncthreads();
    }
    #pragma unroll
    for (int mi = 0; mi < 2; ++mi) {
        const int s0 = w * 32 + mi * 16 + lq * 4;
        float rjv[4];
        #pragma unroll
        for (int r = 0; r < 4; ++r) rjv[r] = rj[b * 128 + s0 + r];
        #pragma unroll
        for (int ni = 0; ni < 8; ++ni) {
            int nn = ni * 16 + lm;
            int z = (n0 + nn) >> 5;
            int q = nn & 31;
            float4 st;
            st.x = acc[mi][ni][0] + rjv[0];
            st.y = acc[mi][ni][1] + rjv[1];
            st.z = acc[mi][ni][2] + rjv[2];
            st.w = acc[mi][ni][3] + rjv[3];
            *(float4*)(outp + (((size_t)(b * C_ + z)) << 12) + 128 * q + s0) = st;
        }
    }
}

// ---------------------------------------------------------------------------
// K6b: out[b,o,p] = sum_z Owh[o,z]·Y[z,p] + ob[o] + x[b,o,p]. grid (32, B).
// ---------------------------------------------------------------------------
__global__ __launch_bounds__(256) void out_kernel(
    float* outp, const u16* __restrict__ Owh, const float* __restrict__ ob,
    const float* __restrict__ x)
{
    const int pt = blockIdx.x, b = blockIdx.y;
    const int p0 = pt * 128;
    const int tid = threadIdx.x;
    const int w = tid >> 6, l = tid & 63, lm = l & 15, lq = l >> 4;

    __shared__ u16 Zs[128 * 136];

    const int zz = tid >> 3;
    const int pp0 = (tid & 7) * 16;
    #pragma unroll
    for (int zb = 0; zb < 128; zb += 32) {
        const int zc = zb + zz;
        const float* yr = outp + (((size_t)(b * C_ + zc)) << 12) + p0 + pp0;
        float vv[16];
        *(float4*)&vv[0]  = *(const float4*)(yr + 0);
        *(float4*)&vv[4]  = *(const float4*)(yr + 4);
        *(float4*)&vv[8]  = *(const float4*)(yr + 8);
        *(float4*)&vv[12] = *(const float4*)(yr + 12);
        const int chb = zc >> 3, zl = zc & 7;
        #pragma unroll
        for (int j = 0; j < 16; ++j) {
            int row = pp0 + j;
            int ch = chb ^ ((row >> 4) & 3);
            Zs[row * 136 + ch * 8 + zl] = f2bs(vv[j]);
        }
    }
    __syncthreads();

    f4v acc[4][8];
    #pragma unroll
    for (int mi = 0; mi < 4; ++mi)
        #pragma unroll
        for (int ni = 0; ni < 8; ++ni) acc[mi][ni] = (f4v){0.f, 0.f, 0.f, 0.f};

    #pragma unroll
    for (int kc = 0; kc < 4; ++kc) {
        s8v af[4];
        #pragma unroll
        for (int mi = 0; mi < 4; ++mi)
            af[mi] = *(const s8v*)(Owh + (size_t)(w * 64 + mi * 16 + lm) * 128
                                   + kc * 32 + lq * 8);
        #pragma unroll
        for (int ni = 0; ni < 8; ++ni) {
            int row = ni * 16 + lm;
            s8v bf = *(const s8v*)&Zs[row * 136 + kc * 32
                                      + ((lq ^ ((row >> 4) & 3)) << 3)];
            #pragma unroll
            for (int mi = 0; mi < 4; ++mi)
                acc[mi][ni] = MFMA16(af[mi], bf, acc[mi][ni]);
        }
    }
    #pragma unroll
    for (int mi = 0; mi < 4; ++mi) {
        #pragma unroll
        for (int r = 0; r < 4; ++r) {
            int o = w * 64 + mi * 16 + lq * 4 + r;
            float bo = ob[o];
            #pragma unroll
            for (int ni = 0; ni < 8; ++ni) {
                int p = p0 + ni * 16 + lm;
                size_t idx = (((size_t)(b * C_ + o)) << 12) + p;
                outp[idx] = acc[mi][ni][r] + bo + x[idx];
            }
        }
    }
}

extern "C" void kernel_launch(void* const* d_in, const int* in_sizes, int n_in,
                              void* d_out, int out_size, void* d_ws, size_t ws_size,
                              hipStream_t stream) {
    const float* x  = (const float*)d_in[0];
    const float* tw = (const float*)d_in[1];
    const float* tb = (const float*)d_in[2];
    const float* pw = (const float*)d_in[3];
    const float* pb = (const float*)d_in[4];
    const float* gw = (const float*)d_in[5];
    const float* gb = (const float*)d_in[6];
    const float* ow = (const float*)d_in[7];
    const float* ob = (const float*)d_in[8];
    float* out = (float*)d_out;

    // workspace:
    //   G   fp32 [B,256,256] @ 0
    //   sx  fp32 [B,256]     @  8,388,608
    //   rj  fp32 [B,128]     @ 14,712,832
    //   Mh  bf16 [B,128,256] @ 14,729,216
    //   Owh bf16 [256,128]   @ 16,826,368
    // d_out scratch (dead before final out_kernel writes):
    //   rows 128..255 of each batch: 8 Gram split-K partials
    //   rows   0..127 of each batch: Y[z,p] fp32 intermediate
    char* ws = (char*)d_ws;
    float* G   = (float*)(ws);
    float* sx  = (float*)(ws + 8388608ull);
    float* rj  = (float*)(ws + 14712832ull);
    u16*   Mh  = (u16*)(ws + 14729216ull);
    u16*   Owh = (u16*)(ws + 16826368ull);

    hipLaunchKernelGGL(sx_kernel, dim3(C_, B_), dim3(64), 0, stream, x, sx);
    hipLaunchKernelGGL(gram_mfma, dim3(2, 2, B_ * 8), dim3(256), 0, stream, x, out);
    hipLaunchKernelGGL(g_reduce, dim3(2048), dim3(256), 0, stream, out, G);
    hipLaunchKernelGGL(mid_kernel, dim3(B_), dim3(512), 0, stream,
                       G, tw, tb, pw, pb, sx, gw, gb, Mh, rj);
    hipLaunchKernelGGL(owh_kernel, dim3(32), dim3(256), 0, stream, ow, Owh);
    hipLaunchKernelGGL(y_kernel, dim3(32, B_), dim3(256), 0, stream, Mh, rj, x, out);
    hipLaunchKernelGGL(out_kernel, dim3(32, B_), dim3(256), 0, stream, out, Owh, ob, x);
}

// Round 5
// 482.136 us; speedup vs baseline: 1.9692x; 1.0710x over previous
//
#include <hip/hip_runtime.h>

#define B_ 32
#define C_ 256
#define CI_ 128
#define N_ 4096

typedef unsigned int u32;
typedef unsigned short u16;
typedef __attribute__((ext_vector_type(8))) short s8v;   // 8 bf16 (4 VGPR)
typedef __attribute__((ext_vector_type(4))) float f4v;   // 4 fp32 acc

__device__ __forceinline__ u16 f2bs(float f) {   // fp32 -> bf16 bits (RNE)
    union { float f; u32 u; } c; c.f = f;
    u32 u = c.u + 0x7FFFu + ((c.u >> 16) & 1u);
    return (u16)(u >> 16);
}
__device__ __forceinline__ float bs2f(u16 s) {   // bf16 bits -> fp32
    union { u32 u; float f; } c; c.u = ((u32)s) << 16; return c.f;
}
// split float -> (hi bf16, lo bf16) with x ~= hi + lo  (RNE both — proven numerics)
__device__ __forceinline__ void split2(float x, u16& h, u16& l) {
    h = f2bs(x);
    l = f2bs(x - bs2f(h));
}

#define MFMA16(a, b, c) __builtin_amdgcn_mfma_f32_16x16x32_bf16((a), (b), (c), 0, 0, 0)

// ---------------------------------------------------------------------------
// K1: row sums sx[b,t] = sum_n X[b,t,n]. grid (C,B), block 64 (one wave).
// ---------------------------------------------------------------------------
__global__ __launch_bounds__(64) void sx_kernel(
    const float* __restrict__ x, float* __restrict__ sx)
{
    const int t = blockIdx.x, b = blockIdx.y, lane = threadIdx.x;
    const float4* row = (const float4*)(x + ((size_t)(b * C_ + t)) * N_);
    float s = 0.f;
    for (int k = lane; k < N_ / 4; k += 64) {
        float4 v = row[k];
        s += v.x + v.y + v.z + v.w;
    }
    #pragma unroll
    for (int off = 32; off > 0; off >>= 1) s += __shfl_down(s, off);
    if (lane == 0) sx[b * C_ + t] = s;
}

// ---------------------------------------------------------------------------
// K2: Gram partials (split-K=8) via MFMA hi/lo 3-pass. grid (2,2,B*8).
// Partials -> d_out scratch rows 128..255 per batch; g_reduce sums into G.
// ---------------------------------------------------------------------------
__global__ __launch_bounds__(256) void gram_mfma(
    const float* __restrict__ x, float* __restrict__ outp)
{
    const int zb = blockIdx.z;
    const int b = zb >> 3, ks = zb & 7;
    const int i0 = blockIdx.y * 128, j0 = blockIdx.x * 128;
    const int tid = threadIdx.x;
    const int w = tid >> 6, l = tid & 63, lm = l & 15, lq = l >> 4;

    __shared__ u16 Ah[128 * 40], Al[128 * 40], Bh[128 * 40], Bl[128 * 40];

    f4v acc[2][8];
    #pragma unroll
    for (int mi = 0; mi < 2; ++mi)
        #pragma unroll
        for (int ni = 0; ni < 8; ++ni) acc[mi][ni] = (f4v){0.f, 0.f, 0.f, 0.f};

    const int srow = tid >> 3;          // 0..31
    const int sc4  = (tid & 7) * 4;     // 0,4,...,28

    const int kbeg = ks * 512, kend = kbeg + 512;
    for (int k0 = kbeg; k0 < kend; k0 += 32) {
        #pragma unroll
        for (int rr = 0; rr < 4; ++rr) {
            int row = rr * 32 + srow;
            float4 va = *(const float4*)(x + (((size_t)(b * C_ + i0 + row)) << 12) + k0 + sc4);
            float4 vb = *(const float4*)(x + (((size_t)(b * C_ + j0 + row)) << 12) + k0 + sc4);
            u16 h0, h1, h2, h3, l0, l1, l2, l3;
            split2(va.x, h0, l0); split2(va.y, h1, l1);
            split2(va.z, h2, l2); split2(va.w, h3, l3);
            *(uint2*)&Ah[row * 40 + sc4] = make_uint2((u32)h0 | ((u32)h1 << 16),
                                                      (u32)h2 | ((u32)h3 << 16));
            *(uint2*)&Al[row * 40 + sc4] = make_uint2((u32)l0 | ((u32)l1 << 16),
                                                      (u32)l2 | ((u32)l3 << 16));
            split2(vb.x, h0, l0); split2(vb.y, h1, l1);
            split2(vb.z, h2, l2); split2(vb.w, h3, l3);
            *(uint2*)&Bh[row * 40 + sc4] = make_uint2((u32)h0 | ((u32)h1 << 16),
                                                      (u32)h2 | ((u32)h3 << 16));
            *(uint2*)&Bl[row * 40 + sc4] = make_uint2((u32)l0 | ((u32)l1 << 16),
                                                      (u32)l2 | ((u32)l3 << 16));
        }
        __syncthreads();

        const int kofs = lq * 8;
        s8v ah[2], al2[2];
        #pragma unroll
        for (int mi = 0; mi < 2; ++mi) {
            int arow = w * 32 + mi * 16 + lm;
            ah[mi]  = *(const s8v*)&Ah[arow * 40 + kofs];
            al2[mi] = *(const s8v*)&Al[arow * 40 + kofs];
        }
        #pragma unroll
        for (int ni = 0; ni < 8; ++ni) {
            int brow = ni * 16 + lm;
            s8v bh = *(const s8v*)&Bh[brow * 40 + kofs];
            s8v bl = *(const s8v*)&Bl[brow * 40 + kofs];
            #pragma unroll
            for (int mi = 0; mi < 2; ++mi) {
                acc[mi][ni] = MFMA16(ah[mi],  bh, acc[mi][ni]);
                acc[mi][ni] = MFMA16(ah[mi],  bl, acc[mi][ni]);
                acc[mi][ni] = MFMA16(al2[mi], bh, acc[mi][ni]);
            }
        }
        __syncthreads();
    }
    float* Gp = outp + (((size_t)(b * 256 + 128)) << 12) + (size_t)ks * 65536;
    #pragma unroll
    for (int mi = 0; mi < 2; ++mi)
        #pragma unroll
        for (int ni = 0; ni < 8; ++ni)
            #pragma unroll
            for (int r = 0; r < 4; ++r) {
                int gi = i0 + w * 32 + mi * 16 + lq * 4 + r;
                int gj = j0 + ni * 16 + lm;
                Gp[(size_t)gi * 256 + gj] = acc[mi][ni][r];
            }
}

// ---------------------------------------------------------------------------
// K2b: G[b] = sum_ks Gp[ks][b]. grid 2048, block 256, float4 per thread.
// ---------------------------------------------------------------------------
__global__ __launch_bounds__(256) void g_reduce(
    const float* __restrict__ outp, float* __restrict__ G)
{
    int f = blockIdx.x * 256 + threadIdx.x;
    int b = f >> 14;
    int r4 = (f & 16383) << 2;
    const float* src = outp + (((size_t)(b * 256 + 128)) << 12) + r4;
    float4 s = *(const float4*)(src);
    #pragma unroll
    for (int k = 1; k < 8; ++k) {
        float4 v = *(const float4*)(src + (size_t)k * 65536);
        s.x += v.x; s.y += v.y; s.z += v.z; s.w += v.w;
    }
    *(float4*)(G + ((size_t)b << 16) + r4) = s;
}

// ---------------------------------------------------------------------------
// K3 (fused mid-chain): per batch, 512 threads (8 waves, 2x4). Phases:
//   0: t1/t2 = Tw·sx, Pw·sx; A: A1=Tw·G -> LDS hi/lo; B: F=A1·Pwᵀ + rank-1;
//   softmax -> fsmᵀ hi/lo; rj; C: Mh = fsmᵀ·Gw -> global bf16.
// ---------------------------------------------------------------------------
__global__ __launch_bounds__(512, 2) void mid_kernel(
    const float* __restrict__ G,
    const float* __restrict__ tw, const float* __restrict__ tb,
    const float* __restrict__ pw, const float* __restrict__ pb,
    const float* __restrict__ sx,
    const float* __restrict__ gw, const float* __restrict__ gb,
    u16* __restrict__ Mh, float* __restrict__ rj)
{
    const int b = blockIdx.x;
    const int tid = threadIdx.x;
    const int w = tid >> 6, l = tid & 63, lm = l & 15, lq = l >> 4;
    const int wr = w >> 2, wc = w & 3;          // wave grid 2 x 4

    __shared__ __attribute__((aligned(16))) char smem[157696];
    float* t12s = (float*)(smem + 155648);       // [256]
    float* sxs  = (float*)(smem + 156672);       // [256]
    u16* TwTh = (u16*)(smem);                    // [128][40]
    u16* TwTl = (u16*)(smem + 10240);
    u16* GTh  = (u16*)(smem + 20480);            // [256][40]
    u16* GTl  = (u16*)(smem + 40960);
    u16* A1h = (u16*)(smem);                     // [128][264]
    u16* A1l = (u16*)(smem + 67584);
    u16* PwTh = (u16*)(smem + 135168);           // [128][40]
    u16* PwTl = (u16*)(smem + 145408);
    float* Ff = (float*)(smem);                  // [128][136]
    u16* fsmTh = (u16*)(smem + 69632);           // [128][136]
    u16* fsmTl = (u16*)(smem + 104448);
    u16* GwTh = (u16*)(smem);                    // [256][40]
    u16* GwTl = (u16*)(smem + 20480);

    // ---------------- phase 0 ----------------
    if (tid < 256) sxs[tid] = sx[b * 256 + tid];
    __syncthreads();
    {
        const int oid = tid >> 1, half = tid & 1;
        const float* wrow = (oid < 128) ? (tw + oid * 256) : (pw + (oid - 128) * 256);
        float s = 0.f;
        for (int t = half * 128; t < half * 128 + 128; ++t) s += wrow[t] * sxs[t];
        s += __shfl_xor(s, 1);
        if (half == 0) t12s[oid] = s;
    }
    __syncthreads();

    // ---------------- phase A: A1 = Tw · G ----------------
    f4v acc[4][4];
    #pragma unroll
    for (int mi = 0; mi < 4; ++mi)
        #pragma unroll
        for (int ni = 0; ni < 4; ++ni) acc[mi][ni] = (f4v){0.f, 0.f, 0.f, 0.f};

    for (int t0 = 0; t0 < C_; t0 += 32) {
        {
            int i = tid >> 2, tg = (tid & 3) * 8;
            float4 v0 = *(const float4*)(tw + i * 256 + t0 + tg);
            float4 v1 = *(const float4*)(tw + i * 256 + t0 + tg + 4);
            u16 h0,h1,h2,h3,l0,l1,l2,l3;
            split2(v0.x,h0,l0); split2(v0.y,h1,l1); split2(v0.z,h2,l2); split2(v0.w,h3,l3);
            *(uint2*)&TwTh[i*40+tg]   = make_uint2((u32)h0|((u32)h1<<16),(u32)h2|((u32)h3<<16));
            *(uint2*)&TwTl[i*40+tg]   = make_uint2((u32)l0|((u32)l1<<16),(u32)l2|((u32)l3<<16));
            split2(v1.x,h0,l0); split2(v1.y,h1,l1); split2(v1.z,h2,l2); split2(v1.w,h3,l3);
            *(uint2*)&TwTh[i*40+tg+4] = make_uint2((u32)h0|((u32)h1<<16),(u32)h2|((u32)h3<<16));
            *(uint2*)&TwTl[i*40+tg+4] = make_uint2((u32)l0|((u32)l1<<16),(u32)l2|((u32)l3<<16));
        }
        {
            int u = tid >> 1, tg = (tid & 1) * 16;
            const float* gp = G + ((size_t)b << 16) + (size_t)u * 256 + t0 + tg;
            #pragma unroll
            for (int q = 0; q < 4; ++q) {
                float4 v = *(const float4*)(gp + q * 4);
                u16 h0,h1,h2,h3,l0,l1,l2,l3;
                split2(v.x,h0,l0); split2(v.y,h1,l1); split2(v.z,h2,l2); split2(v.w,h3,l3);
                *(uint2*)&GTh[u*40+tg+q*4] = make_uint2((u32)h0|((u32)h1<<16),(u32)h2|((u32)h3<<16));
                *(uint2*)&GTl[u*40+tg+q*4] = make_uint2((u32)l0|((u32)l1<<16),(u32)l2|((u32)l3<<16));
            }
        }
        __syncthreads();
        const int kofs = lq * 8;
        s8v ah[4], al[4];
        #pragma unroll
        for (int mi = 0; mi < 4; ++mi) {
            int ai = wr * 64 + mi * 16 + lm;
            ah[mi] = *(const s8v*)&TwTh[ai * 40 + kofs];
            al[mi] = *(const s8v*)&TwTl[ai * 40 + kofs];
        }
        #pragma unroll
        for (int ni = 0; ni < 4; ++ni) {
            int bu = wc * 64 + ni * 16 + lm;
            s8v bh = *(const s8v*)&GTh[bu * 40 + kofs];
            s8v bl = *(const s8v*)&GTl[bu * 40 + kofs];
            #pragma unroll
            for (int mi = 0; mi < 4; ++mi) {
                acc[mi][ni] = MFMA16(ah[mi], bh, acc[mi][ni]);
                acc[mi][ni] = MFMA16(ah[mi], bl, acc[mi][ni]);
                acc[mi][ni] = MFMA16(al[mi], bh, acc[mi][ni]);
            }
        }
        __syncthreads();
    }
    #pragma unroll
    for (int mi = 0; mi < 4; ++mi)
        #pragma unroll
        for (int ni = 0; ni < 4; ++ni)
            #pragma unroll
            for (int r = 0; r < 4; ++r) {
                int i = wr * 64 + mi * 16 + lq * 4 + r;
                int u = wc * 64 + ni * 16 + lm;
                u16 h, lo; split2(acc[mi][ni][r], h, lo);
                A1h[i * 264 + u] = h; A1l[i * 264 + u] = lo;
            }
    __syncthreads();

    // ---------------- phase B: F = A1 · Pwᵀ ----------------
    f4v acc2[4][2];
    #pragma unroll
    for (int mi = 0; mi < 4; ++mi)
        #pragma unroll
        for (int ni = 0; ni < 2; ++ni) acc2[mi][ni] = (f4v){0.f, 0.f, 0.f, 0.f};

    for (int u0 = 0; u0 < C_; u0 += 32) {
        {
            int j = tid >> 2, ug = (tid & 3) * 8;
            float4 v0 = *(const float4*)(pw + j * 256 + u0 + ug);
            float4 v1 = *(const float4*)(pw + j * 256 + u0 + ug + 4);
            u16 h0,h1,h2,h3,l0,l1,l2,l3;
            split2(v0.x,h0,l0); split2(v0.y,h1,l1); split2(v0.z,h2,l2); split2(v0.w,h3,l3);
            *(uint2*)&PwTh[j*40+ug]   = make_uint2((u32)h0|((u32)h1<<16),(u32)h2|((u32)h3<<16));
            *(uint2*)&PwTl[j*40+ug]   = make_uint2((u32)l0|((u32)l1<<16),(u32)l2|((u32)l3<<16));
            split2(v1.x,h0,l0); split2(v1.y,h1,l1); split2(v1.z,h2,l2); split2(v1.w,h3,l3);
            *(uint2*)&PwTh[j*40+ug+4] = make_uint2((u32)h0|((u32)h1<<16),(u32)h2|((u32)h3<<16));
            *(uint2*)&PwTl[j*40+ug+4] = make_uint2((u32)l0|((u32)l1<<16),(u32)l2|((u32)l3<<16));
        }
        __syncthreads();
        const int kofs = lq * 8;
        s8v ah[4], al[4];
        #pragma unroll
        for (int mi = 0; mi < 4; ++mi) {
            int ai = wr * 64 + mi * 16 + lm;
            ah[mi] = *(const s8v*)&A1h[ai * 264 + u0 + kofs];
            al[mi] = *(const s8v*)&A1l[ai * 264 + u0 + kofs];
        }
        #pragma unroll
        for (int ni = 0; ni < 2; ++ni) {
            int bj = wc * 32 + ni * 16 + lm;
            s8v bh = *(const s8v*)&PwTh[bj * 40 + kofs];
            s8v bl = *(const s8v*)&PwTl[bj * 40 + kofs];
            #pragma unroll
            for (int mi = 0; mi < 4; ++mi) {
                acc2[mi][ni] = MFMA16(ah[mi], bh, acc2[mi][ni]);
                acc2[mi][ni] = MFMA16(ah[mi], bl, acc2[mi][ni]);
                acc2[mi][ni] = MFMA16(al[mi], bh, acc2[mi][ni]);
            }
        }
        __syncthreads();
    }
    #pragma unroll
    for (int ni = 0; ni < 2; ++ni) {
        int j = wc * 32 + ni * 16 + lm;
        float pbv = pb[j], t2v = t12s[128 + j];
        #pragma unroll
        for (int mi = 0; mi < 4; ++mi)
            #pragma unroll
            for (int r = 0; r < 4; ++r) {
                int i = wr * 64 + mi * 16 + lq * 4 + r;
                float val = acc2[mi][ni][r] + t12s[i] * pbv
                          + tb[i] * (t2v + 4096.0f * pbv);
                Ff[i * 136 + j] = val;
            }
    }
    __syncthreads();

    // ---------------- softmax -> fsmT hi/lo ----------------
    {
        const int i = tid >> 2, sub = tid & 3;
        float vv[32];
        #pragma unroll
        for (int c = 0; c < 32; ++c) vv[c] = Ff[i * 136 + sub * 32 + c];
        float m = vv[0];
        #pragma unroll
        for (int c = 1; c < 32; ++c) m = fmaxf(m, vv[c]);
        m = fmaxf(m, __shfl_xor(m, 1));
        m = fmaxf(m, __shfl_xor(m, 2));
        float s = 0.f;
        #pragma unroll
        for (int c = 0; c < 32; ++c) { vv[c] = __expf(vv[c] - m); s += vv[c]; }
        s += __shfl_xor(s, 1);
        s += __shfl_xor(s, 2);
        float inv = 1.0f / s;
        #pragma unroll
        for (int c = 0; c < 32; ++c) {
            int j = sub * 32 + c;
            u16 h, lo; split2(vv[c] * inv, h, lo);
            fsmTh[j * 136 + i] = h; fsmTl[j * 136 + i] = lo;
        }
    }
    __syncthreads();

    if (tid < 128) {
        float s = 0.f;
        for (int i = 0; i < 128; ++i)
            s += (bs2f(fsmTh[tid * 136 + i]) + bs2f(fsmTl[tid * 136 + i])) * gb[i];
        rj[b * 128 + tid] = s;
    }

    // ---------------- phase C: Mh = fsmT · GwT ----------------
    f4v acc3[4][4];
    #pragma unroll
    for (int mi = 0; mi < 4; ++mi)
        #pragma unroll
        for (int ni = 0; ni < 4; ++ni) acc3[mi][ni] = (f4v){0.f, 0.f, 0.f, 0.f};

    for (int i0 = 0; i0 < CI_; i0 += 32) {
        {
            int ir = tid >> 4, tg = (tid & 15) * 16;
            const float* gp = gw + (size_t)(i0 + ir) * 256 + tg;
            float vv[16];
            *(float4*)&vv[0]  = *(const float4*)(gp + 0);
            *(float4*)&vv[4]  = *(const float4*)(gp + 4);
            *(float4*)&vv[8]  = *(const float4*)(gp + 8);
            *(float4*)&vv[12] = *(const float4*)(gp + 12);
            const int chb = ir >> 3, il = ir & 7;
            #pragma unroll
            for (int jj = 0; jj < 16; ++jj) {
                int t = tg + jj;
                int ch = chb ^ ((t >> 4) & 3);
                u16 h, lo; split2(vv[jj], h, lo);
                GwTh[t * 40 + ch * 8 + il] = h;
                GwTl[t * 40 + ch * 8 + il] = lo;
            }
        }
        __syncthreads();
        s8v ah[4], al[4];
        #pragma unroll
        for (int mi = 0; mi < 4; ++mi) {
            int aj = wr * 64 + mi * 16 + lm;
            ah[mi] = *(const s8v*)&fsmTh[aj * 136 + i0 + lq * 8];
            al[mi] = *(const s8v*)&fsmTl[aj * 136 + i0 + lq * 8];
        }
        #pragma unroll
        for (int ni = 0; ni < 4; ++ni) {
            int bt = wc * 64 + ni * 16 + lm;
            int co = (lq ^ ((bt >> 4) & 3)) << 3;
            s8v bh = *(const s8v*)&GwTh[bt * 40 + co];
            s8v bl = *(const s8v*)&GwTl[bt * 40 + co];
            #pragma unroll
            for (int mi = 0; mi < 4; ++mi) {
                acc3[mi][ni] = MFMA16(ah[mi], bh, acc3[mi][ni]);
                acc3[mi][ni] = MFMA16(ah[mi], bl, acc3[mi][ni]);
                acc3[mi][ni] = MFMA16(al[mi], bh, acc3[mi][ni]);
            }
        }
        __syncthreads();
    }
    #pragma unroll
    for (int mi = 0; mi < 4; ++mi)
        #pragma unroll
        for (int ni = 0; ni < 4; ++ni)
            #pragma unroll
            for (int r = 0; r < 4; ++r) {
                int j = wr * 64 + mi * 16 + lq * 4 + r;
                int t = wc * 64 + ni * 16 + lm;
                Mh[(size_t)b * 32768 + (size_t)j * 256 + t] = f2bs(acc3[mi][ni][r]);
            }
}

// ---------------------------------------------------------------------------
// K5b: Owh = bf16(ow), [256,128]. grid (32), block 256, 4 elems/thread.
// ---------------------------------------------------------------------------
__global__ __launch_bounds__(256) void owh_kernel(
    const float* __restrict__ ow, u16* __restrict__ Owh)
{
    int i = (blockIdx.x * 256 + threadIdx.x) * 4;
    float4 v = *(const float4*)(ow + i);
    u16 a = f2bs(v.x), b = f2bs(v.y), c = f2bs(v.z), d = f2bs(v.w);
    *(uint2*)&Owh[i] = make_uint2((u32)a | ((u32)b << 16), (u32)c | ((u32)d << 16));
}

// ---------------------------------------------------------------------------
// K6a: W[s,n] = sum_t Mh[s,t]·X[t,n] + rj[s] stored scrambled as
// Y[z, 128q+s] fp32 into out[b, 0:128, :] (scratch). grid (32, B).
// ---------------------------------------------------------------------------
__global__ __launch_bounds__(256) void y_kernel(
    const u16* __restrict__ Mh, const float* __restrict__ rj,
    const float* __restrict__ x, float* __restrict__ outp)
{
    const int nb = blockIdx.x, b = blockIdx.y;
    const int n0 = nb * 128;
    const int tid = threadIdx.x;
    const int w = tid >> 6, l = tid & 63, lm = l & 15, lq = l >> 4;

    __shared__ u16 Bs[128 * 40];

    f4v acc[2][8];
    #pragma unroll
    for (int mi = 0; mi < 2; ++mi)
        #pragma unroll
        for (int ni = 0; ni < 8; ++ni) acc[mi][ni] = (f4v){0.f, 0.f, 0.f, 0.f};

    const int tt = tid >> 3;
    const int nn0 = (tid & 7) * 16;

    for (int t0 = 0; t0 < C_; t0 += 32) {
        const float* xr = x + (((size_t)(b * C_ + t0 + tt)) << 12) + n0 + nn0;
        float vv[16];
        *(float4*)&vv[0]  = *(const float4*)(xr + 0);
        *(float4*)&vv[4]  = *(const float4*)(xr + 4);
        *(float4*)&vv[8]  = *(const float4*)(xr + 8);
        *(float4*)&vv[12] = *(const float4*)(xr + 12);
        const int chb = tt >> 3, tl = tt & 7;
        #pragma unroll
        for (int j = 0; j < 16; ++j) {
            int row = nn0 + j;
            int ch = chb ^ ((row >> 4) & 3);
            Bs[row * 40 + ch * 8 + tl] = f2bs(vv[j]);
        }
        __syncthreads();

        s8v af[2];
        #pragma unroll
        for (int mi = 0; mi < 2; ++mi)
            af[mi] = *(const s8v*)(Mh + (size_t)b * 32768
                     + (size_t)(w * 32 + mi * 16 + lm) * 256 + t0 + lq * 8);
        #pragma unroll
        for (int ni = 0; ni < 8; ++ni) {
            int row = ni * 16 + lm;
            s8v bf = *(const s8v*)&Bs[row * 40 + ((lq ^ ((row >> 4) & 3)) << 3)];
            acc[0][ni] = MFMA16(af[0], bf, acc[0][ni]);
            acc[1][ni] = MFMA16(af[1], bf, acc[1][ni]);
        }
        __syncthreads();
    }
    #pragma unroll
    for (int mi = 0; mi < 2; ++mi) {
        const int s0 = w * 32 + mi * 16 + lq * 4;
        float rjv[4];
        #pragma unroll
        for (int r = 0; r < 4; ++r) rjv[r] = rj[b * 128 + s0 + r];
        #pragma unroll
        for (int ni = 0; ni < 8; ++ni) {
            int nn = ni * 16 + lm;
            int z = (n0 + nn) >> 5;
            int q = nn & 31;
            float4 st;
            st.x = acc[mi][ni][0] + rjv[0];
            st.y = acc[mi][ni][1] + rjv[1];
            st.z = acc[mi][ni][2] + rjv[2];
            st.w = acc[mi][ni][3] + rjv[3];
            *(float4*)(outp + (((size_t)(b * C_ + z)) << 12) + 128 * q + s0) = st;
        }
    }
}

// ---------------------------------------------------------------------------
// K6b: out[b,o,p] = sum_z Owh[o,z]·Y[z,p] + ob[o] + x[b,o,p]. grid (64, B):
// 64-wide p-chunks. Staging: Y tile [128 z][64 p] -> Zs bf16 (XOR swizzle),
// reads only cols p0..p0+63 == the cols this block alone writes (race-free).
// MFMA: acc[4 mi][4 ni] over kc (z). Epilogue: per mi, dump acc -> LDS fp32
// scratch (overlaying dead Zs), then linear read-back with float4 x-load +
// float4 out-store (4x fewer, 4x wider VMEM vs scalar fragment stores).
// ---------------------------------------------------------------------------
__global__ __launch_bounds__(256) void out_kernel(
    float* outp, const u16* __restrict__ Owh, const float* __restrict__ ob,
    const float* __restrict__ x)
{
    const int pt = blockIdx.x, b = blockIdx.y;
    const int p0 = pt * 64;
    const int tid = threadIdx.x;
    const int w = tid >> 6, l = tid & 63, lm = l & 15, lq = l >> 4;

    __shared__ __attribute__((aligned(16))) u16 Zs[64 * 136];   // 17408 B
    float* Fsc = (float*)Zs;                                    // [64][68] overlay

    // ---- stage Y tile [128 z][64 p] -> Zs[p][z] bf16, XOR-swizzled
    const int zz = tid >> 2;             // 0..63
    const int pp0 = (tid & 3) * 16;      // 0,16,32,48
    #pragma unroll
    for (int zb = 0; zb < 128; zb += 64) {
        const int zc = zb + zz;
        const float* yr = outp + (((size_t)(b * C_ + zc)) << 12) + p0 + pp0;
        float vv[16];
        *(float4*)&vv[0]  = *(const float4*)(yr + 0);
        *(float4*)&vv[4]  = *(const float4*)(yr + 4);
        *(float4*)&vv[8]  = *(const float4*)(yr + 8);
        *(float4*)&vv[12] = *(const float4*)(yr + 12);
        const int chb = zc >> 3, zl = zc & 7;
        #pragma unroll
        for (int j = 0; j < 16; ++j) {
            int row = pp0 + j;
            int ch = chb ^ ((row >> 4) & 3);
            Zs[row * 136 + ch * 8 + zl] = f2bs(vv[j]);
        }
    }
    __syncthreads();

    // ---- MFMA: out rows o = w*64+mi*16+..., cols p0..p0+63
    f4v acc[4][4];
    #pragma unroll
    for (int mi = 0; mi < 4; ++mi)
        #pragma unroll
        for (int ni = 0; ni < 4; ++ni) acc[mi][ni] = (f4v){0.f, 0.f, 0.f, 0.f};

    #pragma unroll
    for (int kc = 0; kc < 4; ++kc) {
        s8v af[4];
        #pragma unroll
        for (int mi = 0; mi < 4; ++mi)
            af[mi] = *(const s8v*)(Owh + (size_t)(w * 64 + mi * 16 + lm) * 128
                                   + kc * 32 + lq * 8);
        #pragma unroll
        for (int ni = 0; ni < 4; ++ni) {
            int row = ni * 16 + lm;
            s8v bf = *(const s8v*)&Zs[row * 136 + kc * 32
                                      + ((lq ^ ((row >> 4) & 3)) << 3)];
            #pragma unroll
            for (int mi = 0; mi < 4; ++mi)
                acc[mi][ni] = MFMA16(af[mi], bf, acc[mi][ni]);
        }
    }

    // ---- vectorized epilogue via LDS scratch (Zs dead after MFMA)
    #pragma unroll
    for (int mi = 0; mi < 4; ++mi) {
        __syncthreads();
        // dump fragments: LDS row = w*16 + lq*4 + r (0..63), col = ni*16+lm
        #pragma unroll
        for (int ni = 0; ni < 4; ++ni)
            #pragma unroll
            for (int r = 0; r < 4; ++r)
                Fsc[(w * 16 + lq * 4 + r) * 68 + ni * 16 + lm] = acc[mi][ni][r];
        __syncthreads();
        // linear read-back: g -> row = g>>4 (0..63), c4 = (g&15)*4
        #pragma unroll
        for (int k = 0; k < 4; ++k) {
            int g = tid + 256 * k;
            int row = g >> 4, c4 = (g & 15) * 4;
            float4 v = *(const float4*)&Fsc[row * 68 + c4];
            int o = (row >> 4) * 64 + mi * 16 + (row & 15);
            size_t idx = (((size_t)(b * C_ + o)) << 12) + p0 + c4;
            float4 xv = *(const float4*)(x + idx);
            float bo = ob[o];
            float4 st;
            st.x = v.x + bo + xv.x;
            st.y = v.y + bo + xv.y;
            st.z = v.z + bo + xv.z;
            st.w = v.w + bo + xv.w;
            *(float4*)(outp + idx) = st;
        }
    }
}

extern "C" void kernel_launch(void* const* d_in, const int* in_sizes, int n_in,
                              void* d_out, int out_size, void* d_ws, size_t ws_size,
                              hipStream_t stream) {
    const float* x  = (const float*)d_in[0];
    const float* tw = (const float*)d_in[1];
    const float* tb = (const float*)d_in[2];
    const float* pw = (const float*)d_in[3];
    const float* pb = (const float*)d_in[4];
    const float* gw = (const float*)d_in[5];
    const float* gb = (const float*)d_in[6];
    const float* ow = (const float*)d_in[7];
    const float* ob = (const float*)d_in[8];
    float* out = (float*)d_out;

    // workspace:
    //   G   fp32 [B,256,256] @ 0
    //   sx  fp32 [B,256]     @  8,388,608
    //   rj  fp32 [B,128]     @ 14,712,832
    //   Mh  bf16 [B,128,256] @ 14,729,216
    //   Owh bf16 [256,128]   @ 16,826,368
    // d_out scratch (dead before final out_kernel writes):
    //   rows 128..255 of each batch: 8 Gram split-K partials
    //   rows   0..127 of each batch: Y[z,p] fp32 intermediate
    char* ws = (char*)d_ws;
    float* G   = (float*)(ws);
    float* sx  = (float*)(ws + 8388608ull);
    float* rj  = (float*)(ws + 14712832ull);
    u16*   Mh  = (u16*)(ws + 14729216ull);
    u16*   Owh = (u16*)(ws + 16826368ull);

    hipLaunchKernelGGL(sx_kernel, dim3(C_, B_), dim3(64), 0, stream, x, sx);
    hipLaunchKernelGGL(gram_mfma, dim3(2, 2, B_ * 8), dim3(256), 0, stream, x, out);
    hipLaunchKernelGGL(g_reduce, dim3(2048), dim3(256), 0, stream, out, G);
    hipLaunchKernelGGL(mid_kernel, dim3(B_), dim3(512), 0, stream,
                       G, tw, tb, pw, pb, sx, gw, gb, Mh, rj);
    hipLaunchKernelGGL(owh_kernel, dim3(32), dim3(256), 0, stream, ow, Owh);
    hipLaunchKernelGGL(y_kernel, dim3(32, B_), dim3(256), 0, stream, Mh, rj, x, out);
    hipLaunchKernelGGL(out_kernel, dim3(64, B_), dim3(256), 0, stream, out, Owh, ob, x);
}